// Round 9
// baseline (909.896 us; speedup 1.0000x reference)
//
#include <hip/hip_runtime.h>
#include <cstdint>

#define TT  1024
#define BB  32
#define HH  8
#define DD  32
#define YDN 97
#define INN 256
#define BH  (BB*HH)

typedef float v2f __attribute__((ext_vector_type(2)));
typedef float v4f __attribute__((ext_vector_type(4)));

// packed fp32 FMA (v_pk_fma_f32 on CDNA)
#define PK(acc, a, b) (acc) = __builtin_elementwise_fma((a), (b), (acc))

// LDS barrier: drains lgkmcnt, leaves global loads/stores in flight.
__device__ __forceinline__ void bar_lds() {
    asm volatile("s_waitcnt lgkmcnt(0)\n\ts_barrier" ::: "memory");
}

template<int C>
__device__ __forceinline__ float dppf(float x) {
    return __int_as_float(__builtin_amdgcn_update_dpp(
        0, __float_as_int(x), C, 0xF, 0xF, true));
}
__device__ __forceinline__ float swz16(float x) {
    return __int_as_float(__builtin_amdgcn_ds_swizzle(__float_as_int(x), 0x401F));
}
__device__ __forceinline__ float red_max32(float v) {
    v = fmaxf(v, dppf<0xB1>(v));
    v = fmaxf(v, dppf<0x4E>(v));
    v = fmaxf(v, dppf<0x141>(v));
    v = fmaxf(v, dppf<0x140>(v));
    v = fmaxf(v, swz16(v));
    return v;
}
__device__ __forceinline__ float red_sum32(float v) {
    v += dppf<0xB1>(v);
    v += dppf<0x4E>(v);
    v += dppf<0x141>(v);
    v += dppf<0x140>(v);
    v += swz16(v);
    return v;
}

// exp with overflow guard (values are O(1); clamp never binds in practice)
__device__ __forceinline__ float cexp(float v) {
    return __expf(fminf(v, 60.f));
}
__device__ __forceinline__ float sigm(float v) {
    return __builtin_amdgcn_rcpf(1.f + __expf(-v));
}

// 32-length dot, 4 accumulators (dep depth 4)
__device__ __forceinline__ float dot32(const v2f (&x)[16], const v2f (&w)[16]) {
    v2f a0 = {0.f,0.f}, a1 = {0.f,0.f}, a2 = {0.f,0.f}, a3 = {0.f,0.f};
    #pragma unroll
    for (int g = 0; g < 4; g++) {
        PK(a0, x[4*g],   w[4*g]);
        PK(a1, x[4*g+1], w[4*g+1]);
        PK(a2, x[4*g+2], w[4*g+2]);
        PK(a3, x[4*g+3], w[4*g+3]);
    }
    v2f s = (a0 + a1) + (a2 + a3);
    return s.x + s.y;
}

// in-lane sum of 32 values held as 16 v2f (pure-VALU tree)
__device__ __forceinline__ float sum32(const v2f (&q)[16]) {
    v2f a0 = q[0]+q[1],  a1 = q[2]+q[3],  a2 = q[4]+q[5],   a3 = q[6]+q[7];
    v2f b0 = q[8]+q[9],  b1 = q[10]+q[11],b2 = q[12]+q[13], b3 = q[14]+q[15];
    v2f s = ((a0+a1)+(a2+a3)) + ((b0+b1)+(b2+b3));
    return s.x + s.y;
}

__device__ __forceinline__ void lds_read32x2(const float* a, const float* b,
                                             v2f (&ra)[16], v2f (&rb)[16]) {
    const v4f* ap = (const v4f*)a;
    const v4f* bp = (const v4f*)b;
    #pragma unroll
    for (int j = 0; j < 8; j++) {
        v4f x = ap[j]; ra[2*j] = x.xy; ra[2*j+1] = x.zw;
        v4f y = bp[j]; rb[2*j] = y.xy; rb[2*j+1] = y.zw;
    }
}

// ---------------------------------------------------------------------------
// Kernel 1: x = softmax(h) over last dim (rows of 32)
// ---------------------------------------------------------------------------
__global__ __launch_bounds__(256, 1) void softmax_x_kernel(
    const float* __restrict__ hg, float* __restrict__ xg)
{
    const int row  = blockIdx.x * 8 + (threadIdx.x >> 5);
    const int lane = threadIdx.x & 31;
    float v = hg[(size_t)row * DD + lane];
    float m = red_max32(v);
    float ex = __expf(v - m);
    float sm = red_sum32(ex);
    xg[(size_t)row * DD + lane] = ex * __builtin_amdgcn_rcpf(sm);
}

// ---------------------------------------------------------------------------
// Kernel 2: recurrent SRWM + fast-weight memory. One block (4 waves) per
// (b,h). Round-5 skeleton (single region, 1 barrier/step, lag-1 consumers,
// producer-normalized handoff). Changes vs round-5:
//   - wave2 publishes normalized qhat AND khat (no xswap32 on its tail);
//     all readers form u = qhat - khat via 16 v2f subs.
//   - wave2's readback of its own write moved to the TOP of its next step
//     (reads parity PM): latency overlaps the register-only d1 dot.
//   - wave2 uses the fused update: pre = d1 + bs*(x . khat); the 16-PK
//     state update retires off the serial chain.
//   - wave3 PHASE_D: full-F-column zero-shuffle version (round-8 verified).
// Roles at iteration T:
//   wave0: Wy cols 0-63 -> raw exp(y(T)) into exf_s[P]
//   wave1: Wy cols 64-96 (lanes<=32) + wb (lanes 33-36) -> yv_s[P], beta_s[P]
//   wave2: Wq|Wk -> normalized qhat/khat(T) into u_s/k_s[P]
//   wave3: FWM step T-1 from exf_s/yv_s[PM]; writes Og(T-1)
// ---------------------------------------------------------------------------

#define PREF(XC, S)                                                           \
    {                                                                         \
        const v4f* p = (const v4f*)(xg + ((size_t)(S)*BH + bh)*DD);           \
        _Pragma("unroll")                                                     \
        for (int g = 0; g < 8; g++) {                                         \
            v4f v = p[g];                                                     \
            XC[2*g] = v.xy; XC[2*g+1] = v.zw;                                 \
        }                                                                     \
    }

#define PHASE_D(TP, PM)                                                       \
    if (lane < 32) {                                                          \
        v2f fqh[16], fkh[16];                                                 \
        lds_read32x2(&exf_s[PM][0], &exf_s[PM][32], fqh, fkh);                \
        float fvv = yv_s[PM][lane];                                           \
        float fbp = yv_s[PM][32];                                             \
        float fb  = sigm(fbp);                                                \
        float rrfq = __builtin_amdgcn_rcpf(sum32(fqh));                       \
        float rrfk = __builtin_amdgcn_rcpf(sum32(fkh));                       \
        float vold = rrfk * dot32(fkh, F16);                                  \
        float s    = fb * (fvv - vold) * rrfk;                                \
        v2f s2 = {s, s};                                                      \
        v2f o0 = {0.f,0.f}, o1 = {0.f,0.f}, o2 = {0.f,0.f}, o3 = {0.f,0.f};   \
        _Pragma("unroll")                                                     \
        for (int j = 0; j < 4; j++) {                                         \
            PK(F16[4*j],   s2, fkh[4*j]);   PK(o0, fqh[4*j],   F16[4*j]);     \
            PK(F16[4*j+1], s2, fkh[4*j+1]); PK(o1, fqh[4*j+1], F16[4*j+1]);   \
            PK(F16[4*j+2], s2, fkh[4*j+2]); PK(o2, fqh[4*j+2], F16[4*j+2]);   \
            PK(F16[4*j+3], s2, fkh[4*j+3]); PK(o3, fqh[4*j+3], F16[4*j+3]);   \
        }                                                                     \
        v2f ot = (o0 + o1) + (o2 + o3);                                       \
        Og[((size_t)(TP) * BH + bh) * DD + lane] = (ot.x + ot.y) * rrfq;      \
    }

#define STEP(T, XC, P, PM)                                                    \
  {                                                                           \
    if (wv == 2) {                                                            \
        float pre;                                                            \
        if ((T) > 0) {                                                        \
            v2f qr[16], kr[16];                                               \
            lds_read32x2(&u_s[PM][0], &k_s[PM][0], qr, kr);                   \
            float b12 = beta_s[PM][(lane < 32) ? 1 : 2];                      \
            float d1 = dot32(XC, row2);                                       \
            v2f uu0[16];                                                      \
            _Pragma("unroll")                                                 \
            for (int j = 0; j < 16; j++) uu0[j] = qr[j] - kr[j];              \
            float du  = dot32(uu0, row2);                                     \
            float dxk = dot32(XC, kr);                                        \
            float bs  = b12 * du;                                             \
            pre = d1 + bs * dxk;                                              \
            v2f bs2 = {bs, bs};                                               \
            _Pragma("unroll")                                                 \
            for (int j = 0; j < 16; j++) PK(row2[j], bs2, kr[j]);             \
        } else {                                                              \
            pre = dot32(XC, row2);                                            \
        }                                                                     \
        float ex = cexp(pre);                                                 \
        float sm = red_sum32(ex);      /* per-half sum */                     \
        float nh = ex * __builtin_amdgcn_rcpf(sm);                            \
        if (lane < DD) u_s[P][lane]      = nh;   /* qhat */                   \
        else           k_s[P][lane - DD] = nh;   /* khat */                   \
        if ((T) + 2 < TT) { PREF(XC, (T) + 2) }                               \
    } else if (wv < 2) {                                                      \
        float pre;                                                            \
        if ((T) > 0) {                                                        \
            v2f qr[16], kr[16];                                               \
            lds_read32x2(&u_s[PM][0], &k_s[PM][0], qr, kr);                   \
            float b0 = (wv == 0) ? beta_s[PM][0]                              \
                     : ((lane <= 32) ? beta_s[PM][0] : beta_s[PM][3]);        \
            float d1 = dot32(XC, row2);                                       \
            v2f uu0[16];                                                      \
            _Pragma("unroll")                                                 \
            for (int j = 0; j < 16; j++) uu0[j] = qr[j] - kr[j];              \
            float du  = dot32(uu0, row2);                                     \
            float dxk = dot32(XC, kr);                                        \
            float bs  = b0 * du;                                              \
            pre = d1 + bs * dxk;                                              \
            v2f bs2 = {bs, bs};                                               \
            _Pragma("unroll")                                                 \
            for (int j = 0; j < 16; j++) PK(row2[j], bs2, kr[j]);             \
        } else {                                                              \
            pre = dot32(XC, row2);                                            \
        }                                                                     \
        if (wv == 0) {                                                        \
            exf_s[P][lane] = cexp(pre);                                       \
        } else {                                                              \
            if (lane <= 32)      yv_s[P][lane] = pre;                         \
            else if (lane <= 36) beta_s[P][lane - 33] = sigm(pre);            \
        }                                                                     \
        if ((T) + 2 < TT) { PREF(XC, (T) + 2) }                               \
    } else {                                                                  \
        if ((T) > 0) { PHASE_D((T)-1, PM) }                                   \
    }                                                                         \
    bar_lds();                                                                \
  }

__global__ __launch_bounds__(256, 1) void srwm_fwm_kernel(
    const float* __restrict__ xg,
    const float* __restrict__ Wy_g, const float* __restrict__ Wq_g,
    const float* __restrict__ Wk_g, const float* __restrict__ wb_g,
    const float* __restrict__ sWy_g, const float* __restrict__ sWq_g,
    const float* __restrict__ sWk_g, const float* __restrict__ swb_g,
    const float* __restrict__ F_g,
    float* __restrict__ Og)
{
    const int bh   = blockIdx.x;
    const int hh   = bh & 7;
    const int tid  = threadIdx.x;
    const int wv   = tid >> 6;
    const int lane = tid & 63;

    __shared__ __align__(16) float u_s[2][DD];      // qhat (normalized)
    __shared__ __align__(16) float k_s[2][DD];      // khat (normalized)
    __shared__ __align__(16) float exf_s[2][64];    // raw exp(y[0:64])
    __shared__ __align__(16) float yv_s[2][36];     // raw y[64:96] + y[96]
    __shared__ __align__(16) float beta_s[2][4];    // sigmoid betas

    v2f row2[16];   // state column (waves 0-2)
    v2f F16[16];    // FULL fast-weight column (wave 3, lanes < 32)
    v2f XA[16], XB[16];

    // ---- init state columns ----
    if (wv < 3) {
        const float* wp = nullptr; const float* sp = nullptr; int str = 0;
        if (wv == 0) {
            wp = Wy_g  + (size_t)hh * DD * YDN + lane;
            sp = sWy_g + (size_t)bh * DD * YDN + lane;  str = YDN;
        } else if (wv == 1) {
            if (lane <= 32) {
                wp = Wy_g  + (size_t)hh * DD * YDN + 64 + lane;
                sp = sWy_g + (size_t)bh * DD * YDN + 64 + lane;  str = YDN;
            } else if (lane <= 36) {
                wp = wb_g  + (size_t)hh * DD * 4 + (lane - 33);
                sp = swb_g + (size_t)bh * DD * 4 + (lane - 33);  str = 4;
            }
        } else {
            if (lane < 32) {
                wp = Wq_g  + (size_t)hh * DD * DD + lane;
                sp = sWq_g + (size_t)bh * DD * DD + lane;
            } else {
                wp = Wk_g  + (size_t)hh * DD * DD + (lane - 32);
                sp = sWk_g + (size_t)bh * DD * DD + (lane - 32);
            }
            str = DD;
        }
        #pragma unroll
        for (int d = 0; d < 16; d++) {
            v2f t = {0.f, 0.f};
            if (wp) {
                t.x = wp[(2*d)   * str] + sp[(2*d)   * str];
                t.y = wp[(2*d+1) * str] + sp[(2*d+1) * str];
            }
            row2[d] = t;
        }
        // x(0), x(1)
        const v4f* p0 = (const v4f*)(xg + (size_t)bh * DD);
        const v4f* p1 = (const v4f*)(xg + ((size_t)BH + bh) * DD);
        #pragma unroll
        for (int g = 0; g < 8; g++) {
            v4f a = p0[g], b = p1[g];
            XA[2*g] = a.xy; XA[2*g+1] = a.zw;
            XB[2*g] = b.xy; XB[2*g+1] = b.zw;
        }
    } else {
        // F: lane e (<32) holds full column F[0:32, e]
        if (lane < 32) {
            const float* fp = F_g + (size_t)bh * DD * DD + lane;
            #pragma unroll
            for (int d = 0; d < 16; d++) {
                v2f t;
                t.x = fp[(2*d)   * DD];
                t.y = fp[(2*d+1) * DD];
                F16[d] = t;
            }
        }
    }

    for (int t = 0; t < TT; t += 2) {
        STEP(t,     XA, 0, 1)
        STEP(t + 1, XB, 1, 0)
    }
    // drain: FWM for t = TT-1 (its producers wrote parity 1)
    if (wv == 3) { PHASE_D(TT - 1, 1) }
}

// ---------------------------------------------------------------------------
// Kernel 3: out = h + O @ W_out^T   (M=32768, N=K=256), fp32.
// 128x128 tile, 8x8 microtile: 64 FMA per 4 LDS b128 reads.
// ---------------------------------------------------------------------------
#define GM 128
#define GN 128
#define GK 16

__global__ __launch_bounds__(256, 1) void out_proj_kernel(
    const float* __restrict__ O, const float* __restrict__ W,
    const float* __restrict__ hg, float* __restrict__ outg)
{
    __shared__ float As[GK][GM + 4];
    __shared__ float Bs[GK][GN + 4];
    const int tid = threadIdx.x;
    const int tx  = tid & 15;
    const int ty  = tid >> 4;
    const int r0  = blockIdx.x * GM;
    const int c0  = blockIdx.y * GN;

    float acc[8][8];
    #pragma unroll
    for (int i = 0; i < 8; i++)
        #pragma unroll
        for (int j = 0; j < 8; j++) acc[i][j] = 0.f;

    const int am = tid >> 1;
    const int ak = (tid & 1) * 8;

    for (int k0 = 0; k0 < INN; k0 += GK) {
        float4 a0 = *(const float4*)(O + (size_t)(r0 + am) * INN + k0 + ak);
        float4 a1 = *(const float4*)(O + (size_t)(r0 + am) * INN + k0 + ak + 4);
        float4 b0 = *(const float4*)(W + (size_t)(c0 + am) * INN + k0 + ak);
        float4 b1 = *(const float4*)(W + (size_t)(c0 + am) * INN + k0 + ak + 4);
        As[ak+0][am] = a0.x; As[ak+1][am] = a0.y; As[ak+2][am] = a0.z; As[ak+3][am] = a0.w;
        As[ak+4][am] = a1.x; As[ak+5][am] = a1.y; As[ak+6][am] = a1.z; As[ak+7][am] = a1.w;
        Bs[ak+0][am] = b0.x; Bs[ak+1][am] = b0.y; Bs[ak+2][am] = b0.z; Bs[ak+3][am] = b0.w;
        Bs[ak+4][am] = b1.x; Bs[ak+5][am] = b1.y; Bs[ak+6][am] = b1.z; Bs[ak+7][am] = b1.w;
        __syncthreads();
        #pragma unroll
        for (int k = 0; k < GK; k++) {
            float4 av0 = *(const float4*)&As[k][ty * 8];
            float4 av1 = *(const float4*)&As[k][ty * 8 + 4];
            float4 bv0 = *(const float4*)&Bs[k][tx * 8];
            float4 bv1 = *(const float4*)&Bs[k][tx * 8 + 4];
            float a[8] = {av0.x, av0.y, av0.z, av0.w, av1.x, av1.y, av1.z, av1.w};
            float bb[8] = {bv0.x, bv0.y, bv0.z, bv0.w, bv1.x, bv1.y, bv1.z, bv1.w};
            #pragma unroll
            for (int i = 0; i < 8; i++)
                #pragma unroll
                for (int j = 0; j < 8; j++) acc[i][j] += a[i] * bb[j];
        }
        __syncthreads();
    }

    #pragma unroll
    for (int i = 0; i < 8; i++) {
        size_t r = (size_t)(r0 + ty * 8 + i);
        float4 h0 = *(const float4*)(hg + r * INN + c0 + tx * 8);
        float4 h1 = *(const float4*)(hg + r * INN + c0 + tx * 8 + 4);
        float4 o0, o1;
        o0.x = h0.x + acc[i][0]; o0.y = h0.y + acc[i][1];
        o0.z = h0.z + acc[i][2]; o0.w = h0.w + acc[i][3];
        o1.x = h1.x + acc[i][4]; o1.y = h1.y + acc[i][5];
        o1.z = h1.z + acc[i][6]; o1.w = h1.w + acc[i][7];
        *(float4*)(outg + r * INN + c0 + tx * 8)     = o0;
        *(float4*)(outg + r * INN + c0 + tx * 8 + 4) = o1;
    }
}

// ---------------------------------------------------------------------------
extern "C" void kernel_launch(void* const* d_in, const int* in_sizes, int n_in,
                              void* d_out, int out_size, void* d_ws, size_t ws_size,
                              hipStream_t stream)
{
    (void)in_sizes; (void)n_in; (void)out_size; (void)ws_size;

    const float* hg   = (const float*)d_in[0];
    const float* Wy   = (const float*)d_in[1];
    const float* Wq   = (const float*)d_in[2];
    const float* Wk   = (const float*)d_in[3];
    const float* wb   = (const float*)d_in[4];
    const float* Wout = (const float*)d_in[5];
    const float* sWy  = (const float*)d_in[6];
    const float* sWq  = (const float*)d_in[7];
    const float* sWk  = (const float*)d_in[8];
    const float* swb  = (const float*)d_in[9];
    const float* Fw   = (const float*)d_in[10];
    float* out = (float*)d_out;

    float* xg = (float*)d_ws;                      // (T,B,H,D) fp32
    float* Og = xg + (size_t)TT * BB * INN;        // (T,B,IN)  fp32

    softmax_x_kernel<<<TT * BB * HH / 8, 256, 0, stream>>>(hg, xg);
    srwm_fwm_kernel<<<BB * HH, 256, 0, stream>>>(xg, Wy, Wq, Wk, wb,
                                                 sWy, sWq, sWk, swb, Fw, Og);
    out_proj_kernel<<<dim3(TT * BB / GM, INN / GN), 256, 0, stream>>>(Og, Wout, hg, out);
}

// Round 10
// 755.068 us; speedup vs baseline: 1.2051x; 1.2051x over previous
//
#include <hip/hip_runtime.h>
#include <cstdint>

#define TT  1024
#define BB  32
#define HH  8
#define DD  32
#define YDN 97
#define INN 256
#define BH  (BB*HH)

typedef float v2f __attribute__((ext_vector_type(2)));
typedef float v4f __attribute__((ext_vector_type(4)));

// packed fp32 FMA (v_pk_fma_f32 on CDNA)
#define PK(acc, a, b) (acc) = __builtin_elementwise_fma((a), (b), (acc))

// LDS barrier: drains lgkmcnt, leaves global loads/stores in flight.
__device__ __forceinline__ void bar_lds() {
    asm volatile("s_waitcnt lgkmcnt(0)\n\ts_barrier" ::: "memory");
}
__device__ __forceinline__ void wait_lds() {
    asm volatile("s_waitcnt lgkmcnt(0)" ::: "memory");
}

template<int C>
__device__ __forceinline__ float dppf(float x) {
    return __int_as_float(__builtin_amdgcn_update_dpp(
        0, __float_as_int(x), C, 0xF, 0xF, true));
}
__device__ __forceinline__ float swz16(float x) {
    return __int_as_float(__builtin_amdgcn_ds_swizzle(__float_as_int(x), 0x401F));
}
__device__ __forceinline__ float red_max32(float v) {
    v = fmaxf(v, dppf<0xB1>(v));
    v = fmaxf(v, dppf<0x4E>(v));
    v = fmaxf(v, dppf<0x141>(v));
    v = fmaxf(v, dppf<0x140>(v));
    v = fmaxf(v, swz16(v));
    return v;
}
__device__ __forceinline__ float red_sum32(float v) {
    v += dppf<0xB1>(v);
    v += dppf<0x4E>(v);
    v += dppf<0x141>(v);
    v += dppf<0x140>(v);
    v += swz16(v);
    return v;
}

// exp with overflow guard (values are O(1); clamp never binds in practice)
__device__ __forceinline__ float cexp(float v) {
    return __expf(fminf(v, 60.f));
}
__device__ __forceinline__ float sigm(float v) {
    return __builtin_amdgcn_rcpf(1.f + __expf(-v));
}

// 32-length dot, 4 accumulators (dep depth 4)
__device__ __forceinline__ float dot32(const v2f (&x)[16], const v2f (&w)[16]) {
    v2f a0 = {0.f,0.f}, a1 = {0.f,0.f}, a2 = {0.f,0.f}, a3 = {0.f,0.f};
    #pragma unroll
    for (int g = 0; g < 4; g++) {
        PK(a0, x[4*g],   w[4*g]);
        PK(a1, x[4*g+1], w[4*g+1]);
        PK(a2, x[4*g+2], w[4*g+2]);
        PK(a3, x[4*g+3], w[4*g+3]);
    }
    v2f s = (a0 + a1) + (a2 + a3);
    return s.x + s.y;
}

// in-lane sum of 32 values held as 16 v2f (pure-VALU tree)
__device__ __forceinline__ float sum32(const v2f (&q)[16]) {
    v2f a0 = q[0]+q[1],  a1 = q[2]+q[3],  a2 = q[4]+q[5],   a3 = q[6]+q[7];
    v2f b0 = q[8]+q[9],  b1 = q[10]+q[11],b2 = q[12]+q[13], b3 = q[14]+q[15];
    v2f s = ((a0+a1)+(a2+a3)) + ((b0+b1)+(b2+b3));
    return s.x + s.y;
}

__device__ __forceinline__ void lds_read32x2(const float* a, const float* b,
                                             v2f (&ra)[16], v2f (&rb)[16]) {
    const v4f* ap = (const v4f*)a;
    const v4f* bp = (const v4f*)b;
    #pragma unroll
    for (int j = 0; j < 8; j++) {
        v4f x = ap[j]; ra[2*j] = x.xy; ra[2*j+1] = x.zw;
        v4f y = bp[j]; rb[2*j] = y.xy; rb[2*j+1] = y.zw;
    }
}

// ---------------------------------------------------------------------------
// Kernel 1: x = softmax(h) over last dim (rows of 32)
// ---------------------------------------------------------------------------
__global__ __launch_bounds__(256, 1) void softmax_x_kernel(
    const float* __restrict__ hg, float* __restrict__ xg)
{
    const int row  = blockIdx.x * 8 + (threadIdx.x >> 5);
    const int lane = threadIdx.x & 31;
    float v = hg[(size_t)row * DD + lane];
    float m = red_max32(v);
    float ex = __expf(v - m);
    float sm = red_sum32(ex);
    xg[(size_t)row * DD + lane] = ex * __builtin_amdgcn_rcpf(sm);
}

// ---------------------------------------------------------------------------
// Kernel 2: recurrent SRWM + fast-weight memory. One block (4 waves) per
// (b,h). ROUND-5 skeleton (single region, 1 barrier/step, lag-1 consumers,
// producer-normalized handoff, serial consumer update) with exactly two
// verified chain cuts:
//   1. wave2 publishes normalized qhat AND khat separately (no xswap32 on
//      its serial tail); readers form u = qhat - khat via 16 v2f subs.
//   2. wave3 PHASE_D holds FULL F columns on lanes 0-31: in-lane sums of
//      raw exp(y), zero cross-lane ops (round-8/9 verified body).
// Roles at iteration T:
//   wave0: Wy cols 0-63: update(T-1) -> y dot(T) -> raw exp(y) to exf_s[P]
//   wave1: Wy cols 64-96 (lanes<=32) + wb (lanes 33-36): update(T-1) ->
//          dot(T) -> yv_s[P] raw / beta_s[P] sigmoid
//   wave2: Wq|Wk: update(T-1) w/ carried uu,kk -> dot(T) -> softmax ->
//          qhat/khat to q_s/k_s[P] -> same-wave readback, uu=qq-kk
//   wave3: FWM step T-1 from exf_s/yv_s[PM]; writes Og(T-1)
// ---------------------------------------------------------------------------

#define PREF(XC, S)                                                           \
    {                                                                         \
        const v4f* p = (const v4f*)(xg + ((size_t)(S)*BH + bh)*DD);           \
        _Pragma("unroll")                                                     \
        for (int g = 0; g < 8; g++) {                                         \
            v4f v = p[g];                                                     \
            XC[2*g] = v.xy; XC[2*g+1] = v.zw;                                 \
        }                                                                     \
    }

#define PHASE_D(TP, PM)                                                       \
    if (lane < 32) {                                                          \
        v2f fqh[16], fkh[16];                                                 \
        lds_read32x2(&exf_s[PM][0], &exf_s[PM][32], fqh, fkh);                \
        float fvv = yv_s[PM][lane];                                           \
        float fb  = sigm(yv_s[PM][32]);                                       \
        float rrfq = __builtin_amdgcn_rcpf(sum32(fqh));                       \
        float rrfk = __builtin_amdgcn_rcpf(sum32(fkh));                       \
        float vold = rrfk * dot32(fkh, F16);                                  \
        float s    = fb * (fvv - vold) * rrfk;                                \
        v2f s2 = {s, s};                                                      \
        v2f o0 = {0.f,0.f}, o1 = {0.f,0.f}, o2 = {0.f,0.f}, o3 = {0.f,0.f};   \
        _Pragma("unroll")                                                     \
        for (int j = 0; j < 4; j++) {                                         \
            PK(F16[4*j],   s2, fkh[4*j]);   PK(o0, fqh[4*j],   F16[4*j]);     \
            PK(F16[4*j+1], s2, fkh[4*j+1]); PK(o1, fqh[4*j+1], F16[4*j+1]);   \
            PK(F16[4*j+2], s2, fkh[4*j+2]); PK(o2, fqh[4*j+2], F16[4*j+2]);   \
            PK(F16[4*j+3], s2, fkh[4*j+3]); PK(o3, fqh[4*j+3], F16[4*j+3]);   \
        }                                                                     \
        v2f ot = (o0 + o1) + (o2 + o3);                                       \
        Og[((size_t)(TP) * BH + bh) * DD + lane] = (ot.x + ot.y) * rrfq;      \
    }

#define STEP(T, XC, P, PM)                                                    \
  {                                                                           \
    if (wv == 2) {                                                            \
        if ((T) > 0) {                                                        \
            float b12 = beta_s[PM][(lane < 32) ? 1 : 2];                      \
            float du = dot32(uu, row2);                                       \
            float bs = b12 * du;                                              \
            v2f bs2 = {bs, bs};                                               \
            _Pragma("unroll")                                                 \
            for (int j = 0; j < 16; j++) PK(row2[j], bs2, kk[j]);             \
        }                                                                     \
        float pre = dot32(XC, row2);                                          \
        float ex  = cexp(pre);                                                \
        float sm  = red_sum32(ex);     /* per-half sum */                     \
        float nh  = ex * __builtin_amdgcn_rcpf(sm);                           \
        if (lane < DD) q_s[P][lane]      = nh;   /* qhat */                   \
        else           k_s[P][lane - DD] = nh;   /* khat */                   \
        if ((T) + 2 < TT) { PREF(XC, (T) + 2) }                               \
        wait_lds();   /* same-wave write -> read ordering */                  \
        lds_read32x2(&q_s[P][0], &k_s[P][0], qq, kk);                         \
        _Pragma("unroll")                                                     \
        for (int j = 0; j < 16; j++) uu[j] = qq[j] - kk[j];                   \
    } else if (wv < 2) {                                                      \
        if ((T) > 0) {                                                        \
            v2f qr[16], kr[16];                                               \
            lds_read32x2(&q_s[PM][0], &k_s[PM][0], qr, kr);                   \
            float b0 = (wv == 0) ? beta_s[PM][0]                              \
                     : ((lane <= 32) ? beta_s[PM][0] : beta_s[PM][3]);        \
            v2f ur[16];                                                       \
            _Pragma("unroll")                                                 \
            for (int j = 0; j < 16; j++) ur[j] = qr[j] - kr[j];               \
            float du = dot32(ur, row2);                                       \
            float bs = b0 * du;                                               \
            v2f bs2 = {bs, bs};                                               \
            _Pragma("unroll")                                                 \
            for (int j = 0; j < 16; j++) PK(row2[j], bs2, kr[j]);             \
        }                                                                     \
        float pre = dot32(XC, row2);                                          \
        if (wv == 0) {                                                        \
            exf_s[P][lane] = cexp(pre);                                       \
        } else {                                                              \
            if (lane <= 32)      yv_s[P][lane] = pre;                         \
            else if (lane <= 36) beta_s[P][lane - 33] = sigm(pre);            \
        }                                                                     \
        if ((T) + 2 < TT) { PREF(XC, (T) + 2) }                               \
    } else {                                                                  \
        if ((T) > 0) { PHASE_D((T)-1, PM) }                                   \
    }                                                                         \
    bar_lds();                                                                \
  }

__global__ __launch_bounds__(256, 1) void srwm_fwm_kernel(
    const float* __restrict__ xg,
    const float* __restrict__ Wy_g, const float* __restrict__ Wq_g,
    const float* __restrict__ Wk_g, const float* __restrict__ wb_g,
    const float* __restrict__ sWy_g, const float* __restrict__ sWq_g,
    const float* __restrict__ sWk_g, const float* __restrict__ swb_g,
    const float* __restrict__ F_g,
    float* __restrict__ Og)
{
    const int bh   = blockIdx.x;
    const int hh   = bh & 7;
    const int tid  = threadIdx.x;
    const int wv   = tid >> 6;
    const int lane = tid & 63;

    __shared__ __align__(16) float q_s[2][DD];      // qhat (normalized)
    __shared__ __align__(16) float k_s[2][DD];      // khat (normalized)
    __shared__ __align__(16) float exf_s[2][64];    // raw exp(y[0:64])
    __shared__ __align__(16) float yv_s[2][36];     // raw y[64:96] + y[96]
    __shared__ __align__(16) float beta_s[2][4];    // sigmoid betas

    v2f row2[16];         // state column (waves 0-2)
    v2f F16[16];          // FULL fast-weight column (wave 3, lanes < 32)
    v2f qq[16], kk[16], uu[16];   // wave2 carried qhat/khat/u
    v2f XA[16], XB[16];

    // ---- init state columns ----
    if (wv < 3) {
        const float* wp = nullptr; const float* sp = nullptr; int str = 0;
        if (wv == 0) {
            wp = Wy_g  + (size_t)hh * DD * YDN + lane;
            sp = sWy_g + (size_t)bh * DD * YDN + lane;  str = YDN;
        } else if (wv == 1) {
            if (lane <= 32) {
                wp = Wy_g  + (size_t)hh * DD * YDN + 64 + lane;
                sp = sWy_g + (size_t)bh * DD * YDN + 64 + lane;  str = YDN;
            } else if (lane <= 36) {
                wp = wb_g  + (size_t)hh * DD * 4 + (lane - 33);
                sp = swb_g + (size_t)bh * DD * 4 + (lane - 33);  str = 4;
            }
        } else {
            if (lane < 32) {
                wp = Wq_g  + (size_t)hh * DD * DD + lane;
                sp = sWq_g + (size_t)bh * DD * DD + lane;
            } else {
                wp = Wk_g  + (size_t)hh * DD * DD + (lane - 32);
                sp = sWk_g + (size_t)bh * DD * DD + (lane - 32);
            }
            str = DD;
        }
        #pragma unroll
        for (int d = 0; d < 16; d++) {
            v2f t = {0.f, 0.f};
            if (wp) {
                t.x = wp[(2*d)   * str] + sp[(2*d)   * str];
                t.y = wp[(2*d+1) * str] + sp[(2*d+1) * str];
            }
            row2[d] = t;
        }
        // x(0), x(1)
        const v4f* p0 = (const v4f*)(xg + (size_t)bh * DD);
        const v4f* p1 = (const v4f*)(xg + ((size_t)BH + bh) * DD);
        #pragma unroll
        for (int g = 0; g < 8; g++) {
            v4f a = p0[g], b = p1[g];
            XA[2*g] = a.xy; XA[2*g+1] = a.zw;
            XB[2*g] = b.xy; XB[2*g+1] = b.zw;
        }
    } else {
        // F: lane e (<32) holds full column F[0:32, e]
        if (lane < 32) {
            const float* fp = F_g + (size_t)bh * DD * DD + lane;
            #pragma unroll
            for (int d = 0; d < 16; d++) {
                v2f t;
                t.x = fp[(2*d)   * DD];
                t.y = fp[(2*d+1) * DD];
                F16[d] = t;
            }
        }
    }

    for (int t = 0; t < TT; t += 2) {
        STEP(t,     XA, 0, 1)
        STEP(t + 1, XB, 1, 0)
    }
    // drain: FWM for t = TT-1 (its producers wrote parity 1)
    if (wv == 3) { PHASE_D(TT - 1, 1) }
}

// ---------------------------------------------------------------------------
// Kernel 3: out = h + O @ W_out^T   (M=32768, N=K=256), fp32.
// 128x128 tile, 8x8 microtile: 64 FMA per 4 LDS b128 reads.
// ---------------------------------------------------------------------------
#define GM 128
#define GN 128
#define GK 16

__global__ __launch_bounds__(256, 1) void out_proj_kernel(
    const float* __restrict__ O, const float* __restrict__ W,
    const float* __restrict__ hg, float* __restrict__ outg)
{
    __shared__ float As[GK][GM + 4];
    __shared__ float Bs[GK][GN + 4];
    const int tid = threadIdx.x;
    const int tx  = tid & 15;
    const int ty  = tid >> 4;
    const int r0  = blockIdx.x * GM;
    const int c0  = blockIdx.y * GN;

    float acc[8][8];
    #pragma unroll
    for (int i = 0; i < 8; i++)
        #pragma unroll
        for (int j = 0; j < 8; j++) acc[i][j] = 0.f;

    const int am = tid >> 1;
    const int ak = (tid & 1) * 8;

    for (int k0 = 0; k0 < INN; k0 += GK) {
        float4 a0 = *(const float4*)(O + (size_t)(r0 + am) * INN + k0 + ak);
        float4 a1 = *(const float4*)(O + (size_t)(r0 + am) * INN + k0 + ak + 4);
        float4 b0 = *(const float4*)(W + (size_t)(c0 + am) * INN + k0 + ak);
        float4 b1 = *(const float4*)(W + (size_t)(c0 + am) * INN + k0 + ak + 4);
        As[ak+0][am] = a0.x; As[ak+1][am] = a0.y; As[ak+2][am] = a0.z; As[ak+3][am] = a0.w;
        As[ak+4][am] = a1.x; As[ak+5][am] = a1.y; As[ak+6][am] = a1.z; As[ak+7][am] = a1.w;
        Bs[ak+0][am] = b0.x; Bs[ak+1][am] = b0.y; Bs[ak+2][am] = b0.z; Bs[ak+3][am] = b0.w;
        Bs[ak+4][am] = b1.x; Bs[ak+5][am] = b1.y; Bs[ak+6][am] = b1.z; Bs[ak+7][am] = b1.w;
        __syncthreads();
        #pragma unroll
        for (int k = 0; k < GK; k++) {
            float4 av0 = *(const float4*)&As[k][ty * 8];
            float4 av1 = *(const float4*)&As[k][ty * 8 + 4];
            float4 bv0 = *(const float4*)&Bs[k][tx * 8];
            float4 bv1 = *(const float4*)&Bs[k][tx * 8 + 4];
            float a[8] = {av0.x, av0.y, av0.z, av0.w, av1.x, av1.y, av1.z, av1.w};
            float bb[8] = {bv0.x, bv0.y, bv0.z, bv0.w, bv1.x, bv1.y, bv1.z, bv1.w};
            #pragma unroll
            for (int i = 0; i < 8; i++)
                #pragma unroll
                for (int j = 0; j < 8; j++) acc[i][j] += a[i] * bb[j];
        }
        __syncthreads();
    }

    #pragma unroll
    for (int i = 0; i < 8; i++) {
        size_t r = (size_t)(r0 + ty * 8 + i);
        float4 h0 = *(const float4*)(hg + r * INN + c0 + tx * 8);
        float4 h1 = *(const float4*)(hg + r * INN + c0 + tx * 8 + 4);
        float4 o0, o1;
        o0.x = h0.x + acc[i][0]; o0.y = h0.y + acc[i][1];
        o0.z = h0.z + acc[i][2]; o0.w = h0.w + acc[i][3];
        o1.x = h1.x + acc[i][4]; o1.y = h1.y + acc[i][5];
        o1.z = h1.z + acc[i][6]; o1.w = h1.w + acc[i][7];
        *(float4*)(outg + r * INN + c0 + tx * 8)     = o0;
        *(float4*)(outg + r * INN + c0 + tx * 8 + 4) = o1;
    }
}

// ---------------------------------------------------------------------------
extern "C" void kernel_launch(void* const* d_in, const int* in_sizes, int n_in,
                              void* d_out, int out_size, void* d_ws, size_t ws_size,
                              hipStream_t stream)
{
    (void)in_sizes; (void)n_in; (void)out_size; (void)ws_size;

    const float* hg   = (const float*)d_in[0];
    const float* Wy   = (const float*)d_in[1];
    const float* Wq   = (const float*)d_in[2];
    const float* Wk   = (const float*)d_in[3];
    const float* wb   = (const float*)d_in[4];
    const float* Wout = (const float*)d_in[5];
    const float* sWy  = (const float*)d_in[6];
    const float* sWq  = (const float*)d_in[7];
    const float* sWk  = (const float*)d_in[8];
    const float* swb  = (const float*)d_in[9];
    const float* Fw   = (const float*)d_in[10];
    float* out = (float*)d_out;

    float* xg = (float*)d_ws;                      // (T,B,H,D) fp32
    float* Og = xg + (size_t)TT * BB * INN;        // (T,B,IN)  fp32

    softmax_x_kernel<<<TT * BB * HH / 8, 256, 0, stream>>>(hg, xg);
    srwm_fwm_kernel<<<BB * HH, 256, 0, stream>>>(xg, Wy, Wq, Wk, wb,
                                                 sWy, sWq, sWk, swb, Fw, Og);
    out_proj_kernel<<<dim3(TT * BB / GM, INN / GN), 256, 0, stream>>>(Og, Wout, hg, out);
}